// Round 2
// baseline (458.348 us; speedup 1.0000x reference)
//
#include <hip/hip_runtime.h>
#include <cstdint>

// ============================================================================
// Gtu: u=silu(x@Wu+bu); v=silu(x@Wv+bv); per-channel causal conv of v with
// RPE-generated decayed kernel (rfft4096 via packed cfft2048); out=(u*conv)@Wo+bo
// R9: XCD-aware chunked block swizzle (T1) on both big GEMMs, the small RPE
// GEMMs, and the FFT kernels. MI355X round-robins blockIdx across 8 XCDs;
// remapping lbid=(bid%8)*(nwg/8)+bid/8 gives each XCD a contiguous tile chunk
// so A-strips / B-panels / af spectra become L2-resident per XCD.
// (R8: in-place register-staged Stockham FFT, 32KiB LDS/block.)
// ============================================================================

typedef unsigned short ushort_t;                                    // bf16 bits
typedef __attribute__((ext_vector_type(8))) short short8;           // MFMA A/B frag
typedef __attribute__((ext_vector_type(4))) float f32x4;            // MFMA acc

#define AS1 __attribute__((address_space(1)))
#define AS3 __attribute__((address_space(3)))

// per-buffer swizzles (bijections on [0,2048) float2 indices) [R4 HW-verified]
#define SW1(j) ((j) ^ (((j) >> 4) & 15))        // stage1-output positions
#define SW2(j) ((j) ^ ((((j) >> 6) & 7) << 1))  // stage2-output positions

// XCD-aware chunked swizzle: bijective when nwg % 8 == 0 (all our grids are).
// Physical bid b runs on XCD (b%8); logical tile (b%8)*(nwg/8)+b/8 gives each
// XCD a contiguous chunk of logical tiles -> operand reuse stays in its L2.
__device__ __forceinline__ int xcd_swz(int bid, int nwg) {
  return (bid & 7) * (nwg >> 3) + (bid >> 3);
}

__device__ __forceinline__ float bf2f(ushort_t b) {
  union { unsigned u; float f; } x; x.u = ((unsigned)b) << 16; return x.f;
}
__device__ __forceinline__ ushort_t f2bf(float f) {
  union { float f; unsigned u; } x; x.f = f;
  unsigned r = x.u + 0x7fffu + ((x.u >> 16) & 1u);   // RNE
  return (ushort_t)(r >> 16);
}

// CK-style addrspace cast (flat LDS addr low 32 bits == LDS offset on gfx9)
__device__ __forceinline__ void gload_lds16(const void* g, void* l) {
  auto gp = reinterpret_cast<const AS1 unsigned*>(reinterpret_cast<uintptr_t>(g));
  auto lp = reinterpret_cast<AS3 unsigned*>(reinterpret_cast<uintptr_t>(l));
  __builtin_amdgcn_global_load_lds(gp, lp, 16, 0, 0);
}

// ---------------------------------------------------------------------------
// bf16 GEMM: C = A[M][K] @ Bt[N][K]^T (+bias). 128x128x64 tiles, 4 waves.
// MODE 0: fp32 store. MODE 3: silu; col<1536 -> u; col>=1536 -> vt transposed.
// ---------------------------------------------------------------------------
template<int MODE>
__launch_bounds__(256, 2)
__global__ void gemm_bt(const ushort_t* __restrict__ A, const ushort_t* __restrict__ Bt,
                        const float* __restrict__ bias, void* __restrict__ Cout,
                        void* __restrict__ Cout2, int M, int N, int K, float lng)
{
  __shared__ ushort_t As[128 * 64];
  __shared__ ushort_t Bs[128 * 64];
  const int tid  = threadIdx.x;
  const int wave = tid >> 6, lane = tid & 63;
  const int nb = N >> 7;
  const int lbid = xcd_swz((int)blockIdx.x, (int)gridDim.x);
  const int bm = lbid / nb, bn = lbid % nb;
  const int m0 = bm << 7, n0 = bn << 7;
  const int lrow = lane & 15, quad = lane >> 4;
  const int wm = (wave >> 1) << 6, wn = (wave & 1) << 6;
  const int srow = lane >> 3;
  const int scol = (lane & 7) << 3;

  f32x4 acc[4][4] = {};

  for (int kt = 0; kt < K; kt += 64) {
    __syncthreads();
#pragma unroll
    for (int i = 0; i < 4; ++i) {
      const int ci  = i * 4 + wave;
      const int row = ci * 8 + srow;
      gload_lds16(A  + (long)(m0 + row) * K + kt + scol, (void*)&As[ci * 512]);
      gload_lds16(Bt + (long)(n0 + row) * K + kt + scol, (void*)&Bs[ci * 512]);
    }
    __syncthreads();
#pragma unroll
    for (int s = 0; s < 2; ++s) {
      short8 afr[4], bfr[4];
#pragma unroll
      for (int i = 0; i < 4; ++i)
        afr[i] = *(const short8*)&As[(wm + i * 16 + lrow) * 64 + s * 32 + quad * 8];
#pragma unroll
      for (int j = 0; j < 4; ++j)
        bfr[j] = *(const short8*)&Bs[(wn + j * 16 + lrow) * 64 + s * 32 + quad * 8];
#pragma unroll
      for (int i = 0; i < 4; ++i)
#pragma unroll
        for (int j = 0; j < 4; ++j)
          acc[i][j] = __builtin_amdgcn_mfma_f32_16x16x32_bf16(afr[i], bfr[j], acc[i][j], 0, 0, 0);
    }
  }

#pragma unroll
  for (int i = 0; i < 4; ++i) {
    const int rowb = m0 + wm + i * 16 + quad * 4;
#pragma unroll
    for (int j = 0; j < 4; ++j) {
      const int col = n0 + wn + j * 16 + lrow;
      const float bv = bias[col];
      if (MODE == 0) {
#pragma unroll
        for (int r = 0; r < 4; ++r)
          ((float*)Cout)[(long)(rowb + r) * N + col] = acc[i][j][r] + bv;
      } else {  // MODE 3
        if (col < 1536) {
#pragma unroll
          for (int r = 0; r < 4; ++r) {
            float val = acc[i][j][r] + bv;
            float sv = val / (1.f + __expf(-val));
            ((ushort_t*)Cout)[(long)(rowb + r) * 1536 + col] = f2bf(sv);
          }
        } else {
          union { ushort_t h[4]; uint2 u2; } pk;
#pragma unroll
          for (int r = 0; r < 4; ++r) {
            float val = acc[i][j][r] + bv;
            float sv = val / (1.f + __expf(-val));
            pk.h[r] = f2bf(sv);
          }
          *(uint2*)((ushort_t*)Cout2 + (long)(col - 1536) * 16384 + rowb) = pk.u2;
        }
      }
    }
  }
}

// ---------------------------------------------------------------------------
// Small-GEMM variant: 64x64 tiles, 4 waves (each 32x32). Same staging scheme.
// MODE 0: fp32 store. MODE 2: *gamma^row, transposed fp32 store (RPE kernel).
// ---------------------------------------------------------------------------
template<int MODE>
__launch_bounds__(256, 2)
__global__ void gemm64_bt(const ushort_t* __restrict__ A, const ushort_t* __restrict__ Bt,
                          const float* __restrict__ bias, float* __restrict__ Cout,
                          int M, int N, int K, float lng)
{
  __shared__ ushort_t As[64 * 64];
  __shared__ ushort_t Bs[64 * 64];
  const int tid = threadIdx.x, wave = tid >> 6, lane = tid & 63;
  const int nb = N >> 6;
  const int lbid = xcd_swz((int)blockIdx.x, (int)gridDim.x);
  const int bm = lbid / nb, bn = lbid % nb;
  const int m0 = bm << 6, n0 = bn << 6;
  const int lrow = lane & 15, quad = lane >> 4;
  const int wm = (wave >> 1) << 5, wn = (wave & 1) << 5;
  const int srow = lane >> 3, scol = (lane & 7) << 3;

  f32x4 acc[2][2] = {};

  for (int kt = 0; kt < K; kt += 64) {
    __syncthreads();
#pragma unroll
    for (int i = 0; i < 2; ++i) {
      const int ci = i * 4 + wave;          // 8 chunks of 8 rows
      const int row = ci * 8 + srow;
      gload_lds16(A  + (long)(m0 + row) * K + kt + scol, (void*)&As[ci * 512]);
      gload_lds16(Bt + (long)(n0 + row) * K + kt + scol, (void*)&Bs[ci * 512]);
    }
    __syncthreads();
#pragma unroll
    for (int s = 0; s < 2; ++s) {
      short8 afr[2], bfr[2];
#pragma unroll
      for (int i = 0; i < 2; ++i)
        afr[i] = *(const short8*)&As[(wm + i * 16 + lrow) * 64 + s * 32 + quad * 8];
#pragma unroll
      for (int j = 0; j < 2; ++j)
        bfr[j] = *(const short8*)&Bs[(wn + j * 16 + lrow) * 64 + s * 32 + quad * 8];
#pragma unroll
      for (int i = 0; i < 2; ++i)
#pragma unroll
        for (int j = 0; j < 2; ++j)
          acc[i][j] = __builtin_amdgcn_mfma_f32_16x16x32_bf16(afr[i], bfr[j], acc[i][j], 0, 0, 0);
    }
  }

#pragma unroll
  for (int i = 0; i < 2; ++i) {
    const int rowb = m0 + wm + i * 16 + quad * 4;
#pragma unroll
    for (int j = 0; j < 2; ++j) {
      const int col = n0 + wn + j * 16 + lrow;
      const float bv = bias[col];
#pragma unroll
      for (int r = 0; r < 4; ++r) {
        const int row = rowb + r;
        float val = acc[i][j][r] + bv;
        if (MODE == 0) Cout[(long)row * N + col] = val;
        else           Cout[(long)col * M + row] = val * __expf(lng * (float)row);
      }
    }
  }
}

// ---------------------------------------------------------------------------
// RPE row op: srms -> relu -> bf16
// ---------------------------------------------------------------------------
__device__ __forceinline__ void srms_relu_store(float v0, float v1, ushort_t* out,
                                                long rowbase, int tid)
{
  float ss = v0 * v0 + v1 * v1;
#pragma unroll
  for (int off = 32; off; off >>= 1) ss += __shfl_down(ss, off);
  __shared__ float ps[4];
  const int wave = tid >> 6, lane = tid & 63;
  if (lane == 0) ps[wave] = ss;
  __syncthreads();
  float tot = ps[0] + ps[1] + ps[2] + ps[3];
  float sc = 1.f / (sqrtf(tot * (1.f / 512.f)) + 1e-6f);
  out[rowbase + tid]       = f2bf(fmaxf(v0 * sc, 0.f));
  out[rowbase + tid + 256] = f2bf(fmaxf(v1 * sc, 0.f));
}

__launch_bounds__(256)
__global__ void rpe_norm(const float* __restrict__ h, ushort_t* __restrict__ out)
{
  const int n = blockIdx.x, tid = threadIdx.x;
  float v0 = h[(long)n * 512 + tid];
  float v1 = h[(long)n * 512 + tid + 256];
  srms_relu_store(v0, v1, out, (long)n * 512, tid);
}

// ---------------------------------------------------------------------------
// Merged prep: 6x weight transpose | bias concat | x->bf16 | twiddles | rpe_h0
// ---------------------------------------------------------------------------
__device__ __forceinline__ void wtrans_body(const float* __restrict__ src,
                                            ushort_t* __restrict__ dst,
                                            int K, int N, int lb, int tid,
                                            float (*tile)[33])
{
  const int nbx = N >> 5;
  const int bx = lb % nbx, by = lb / nbx;
  const int n0 = bx << 5, k0 = by << 5;
  const int tx = tid & 31, ty = tid >> 5;
  for (int yy = ty; yy < 32; yy += 8)
    tile[yy][tx] = src[(long)(k0 + yy) * N + n0 + tx];
  __syncthreads();
  for (int yy = ty; yy < 32; yy += 8)
    dst[(long)(n0 + yy) * K + k0 + tx] = f2bf(tile[tx][yy]);
}

__launch_bounds__(256)
__global__ void prep_all(const float* __restrict__ Wu, const float* __restrict__ Wv,
                         const float* __restrict__ Wo, const float* __restrict__ rW,
                         const float* __restrict__ rWout,
                         const float* __restrict__ bu, const float* __restrict__ bv,
                         const float* __restrict__ x,
                         const float* __restrict__ rWin, const float* __restrict__ rbin,
                         ushort_t* __restrict__ wuvt, ushort_t* __restrict__ wot,
                         ushort_t* __restrict__ wrt, ushort_t* __restrict__ wroutt,
                         float* __restrict__ buvb, ushort_t* __restrict__ xb,
                         float2* __restrict__ twg, float2* __restrict__ twh,
                         ushort_t* __restrict__ a0)
{
  __shared__ float tile[32][33];
  const int bid = blockIdx.x, tid = threadIdx.x;
  if (bid < 3840) {
    const float* src; ushort_t* dst; int K, N, lb;
    if (bid < 768)       { src = Wu;    dst = wuvt;              K = 512;  N = 1536; lb = bid; }
    else if (bid < 1536) { src = Wv;    dst = wuvt + 1536L*512;  K = 512;  N = 1536; lb = bid - 768; }
    else if (bid < 2304) { src = Wo;    dst = wot;               K = 1536; N = 512;  lb = bid - 1536; }
    else if (bid < 2560) { src = rW;              dst = wrt;              K = 512; N = 512; lb = bid - 2304; }
    else if (bid < 2816) { src = rW + 512L*512;   dst = wrt + 512L*512;   K = 512; N = 512; lb = bid - 2560; }
    else if (bid < 3072) { src = rW + 2L*512*512; dst = wrt + 2L*512*512; K = 512; N = 512; lb = bid - 2816; }
    else                 { src = rWout; dst = wroutt;            K = 512;  N = 1536; lb = bid - 3072; }
    wtrans_body(src, dst, K, N, lb, tid, tile);
  } else if (bid < 3846) {
    int i = (bid - 3840) * 256 + tid;
    if (i < 1536) { buvb[i] = bu[i]; buvb[1536 + i] = bv[i]; }
  } else if (bid < 12038) {
    long i = (long)(bid - 3846) * 1024 + tid * 4;
    float4 f = *(const float4*)(x + i);
    unsigned lo = (unsigned)f2bf(f.x) | ((unsigned)f2bf(f.y) << 16);
    unsigned hi = (unsigned)f2bf(f.z) | ((unsigned)f2bf(f.w) << 16);
    *(uint2*)(xb + i) = make_uint2(lo, hi);
  } else if (bid < 12046) {
    int j = (bid - 12038) * 256 + tid;    // 0..2047
    float s, c;
    __sincosf((float)j * (6.283185307179586f / 2048.f), &s, &c);
    twg[j] = make_float2(c, -s);
    float s2, c2;
    __sincosf((float)j * (3.14159265358979f / 2048.f), &s2, &c2);
    twh[j] = make_float2(c2, -s2);
  } else {
    const int n = bid - 12046;            // 0..2047
    const float fn = (float)n;
    float v0 = fn * rWin[tid] + rbin[tid];
    float v1 = fn * rWin[tid + 256] + rbin[tid + 256];
    srms_relu_store(v0, v1, a0, (long)n * 512, tid);
  }
}

// ---------------------------------------------------------------------------
// Block-level Stockham FFT-2048 (radix 8,8,8,4), TWO sequences at once,
// IN PLACE (R8): each stage reads its 8 elems/thread into registers,
// barriers, then writes back to the SAME buffer at R4's Stockham output
// positions (SW1/SW2 swizzles preserved). Stage 4 is per-thread in-place.
// ---------------------------------------------------------------------------
__device__ __forceinline__ float2 cmulf(float2 a, float2 b) {
  return make_float2(a.x * b.x - a.y * b.y, a.x * b.y + a.y * b.x);
}
__device__ __forceinline__ float2 cadd(float2 a, float2 b){ return make_float2(a.x+b.x, a.y+b.y); }
__device__ __forceinline__ float2 csub(float2 a, float2 b){ return make_float2(a.x-b.x, a.y-b.y); }
__device__ __forceinline__ float2 cmni(float2 z){ return make_float2(z.y, -z.x); }     // z * (-i)
__device__ __forceinline__ float2 cw8(float2 z){   // z * cis(-pi/4)
  const float s = 0.70710678118654752f;
  return make_float2(s*(z.x+z.y), s*(z.y-z.x));
}
__device__ __forceinline__ float2 cw83(float2 z){  // z * cis(-3pi/4)
  const float s = 0.70710678118654752f;
  return make_float2(s*(z.y-z.x), -s*(z.x+z.y));
}

// DFT-8 combine (twiddles pre-applied) [R4 HW-verified]
__device__ __forceinline__ void dft8(const float2* u, float2* y)
{
  float2 a0=cadd(u[0],u[4]), a1=cadd(u[1],u[5]), a2=cadd(u[2],u[6]), a3=cadd(u[3],u[7]);
  float2 b0=csub(u[0],u[4]), b1=cw8(csub(u[1],u[5])), b2=cmni(csub(u[2],u[6])), b3=cw83(csub(u[3],u[7]));
  float2 c0=cadd(a0,a2), c1=csub(a0,a2), c2=cadd(a1,a3), c3=cmni(csub(a1,a3));
  y[0]=cadd(c0,c2); y[2]=cadd(c1,c3); y[4]=csub(c0,c2); y[6]=csub(c1,c3);
  float2 d0=cadd(b0,b2), d1=csub(b0,b2), d2=cadd(b1,b3), d3=cmni(csub(b1,b3));
  y[1]=cadd(d0,d2); y[3]=cadd(d1,d3); y[5]=csub(d0,d2); y[7]=csub(d1,d3);
}
__device__ __forceinline__ void dft8_hz(const float2* u, float2* y)   // u[4..7]=0
{
  float2 b1=cw8(u[1]), b2=cmni(u[2]), b3=cw83(u[3]);
  float2 c0=cadd(u[0],u[2]), c1=csub(u[0],u[2]), c2=cadd(u[1],u[3]), c3=cmni(csub(u[1],u[3]));
  y[0]=cadd(c0,c2); y[2]=cadd(c1,c3); y[4]=csub(c0,c2); y[6]=csub(c1,c3);
  float2 d0=cadd(u[0],b2), d1=csub(u[0],b2), d2=cadd(b1,b3), d3=cmni(csub(b1,b3));
  y[1]=cadd(d0,d2); y[3]=cadd(d1,d3); y[5]=csub(d0,d2); y[7]=csub(d1,d3);
}

template<bool HZ>
__device__ void fft2048_ip2(float2* ba, float2* bb,
                            const float2* __restrict__ tw, int tid)
{
  float2 u[8], v[8], y[8], z[8];
  // ---- stage 1: radix-8, p=1 (no twiddles) ----
  {
    const int i = tid;
#pragma unroll
    for (int m = 0; m < (HZ ? 4 : 8); ++m) { u[m] = ba[i + 256*m]; v[m] = bb[i + 256*m]; }
    if (HZ) { dft8_hz(u, y); dft8_hz(v, z); } else { dft8(u, y); dft8(v, z); }
    __syncthreads();                         // all reads done before any write
    const int j = i << 3;
#pragma unroll
    for (int m = 0; m < 8; ++m) { ba[SW1(j + m)] = y[m]; bb[SW1(j + m)] = z[m]; }
  }
  __syncthreads();
  // ---- stage 2: radix-8, p=8 (tw step 32) ----
  {
    const int i = tid, k = i & 7, tb = k << 5;
    float2 w[8];
#pragma unroll
    for (int m = 1; m < 8; ++m) w[m] = tw[m * tb];
#pragma unroll
    for (int m = 0; m < 8; ++m) { u[m] = ba[SW1(i + 256*m)]; v[m] = bb[SW1(i + 256*m)]; }
#pragma unroll
    for (int m = 1; m < 8; ++m) { u[m] = cmulf(u[m], w[m]); v[m] = cmulf(v[m], w[m]); }
    dft8(u, y); dft8(v, z);
    __syncthreads();
    const int j = ((i - k) << 3) + k;
#pragma unroll
    for (int m = 0; m < 8; ++m) { ba[SW2(j + 8*m)] = y[m]; bb[SW2(j + 8*m)] = z[m]; }
  }
  __syncthreads();
  // ---- stage 3: radix-8, p=64 (tw step 4) ----
  {
    const int i = tid, k = i & 63, tb = k << 2;
    float2 w[8];
#pragma unroll
    for (int m = 1; m < 8; ++m) w[m] = tw[m * tb];
#pragma unroll
    for (int m = 0; m < 8; ++m) { u[m] = ba[SW2(i + 256*m)]; v[m] = bb[SW2(i + 256*m)]; }
#pragma unroll
    for (int m = 1; m < 8; ++m) { u[m] = cmulf(u[m], w[m]); v[m] = cmulf(v[m], w[m]); }
    dft8(u, y); dft8(v, z);
    __syncthreads();
    const int j = ((i - k) << 3) + k;
#pragma unroll
    for (int m = 0; m < 8; ++m) { ba[j + 64*m] = y[m]; bb[j + 64*m] = z[m]; }
  }
  __syncthreads();
  // ---- stage 4: radix-4, p=512 (k=i, j=i): per-thread in-place ----
#pragma unroll
  for (int hh = 0; hh < 2; ++hh) {
    const int i = tid + (hh << 8);
    float2 w1 = tw[i], w2 = tw[2 * i], w3 = tw[3 * i];
    float2 q0 = ba[i], q1 = ba[i + 512], q2 = ba[i + 1024], q3 = ba[i + 1536];
    float2 r0 = bb[i], r1 = bb[i + 512], r2 = bb[i + 1024], r3 = bb[i + 1536];
    q1 = cmulf(q1, w1); q2 = cmulf(q2, w2); q3 = cmulf(q3, w3);
    r1 = cmulf(r1, w1); r2 = cmulf(r2, w2); r3 = cmulf(r3, w3);
    {
      float2 v0 = cadd(q0, q2), v2 = csub(q0, q2);
      float2 v1 = cadd(q1, q3), v3 = cmni(csub(q1, q3));
      ba[i]        = cadd(v0, v1);
      ba[i + 512]  = cadd(v2, v3);
      ba[i + 1024] = csub(v0, v1);
      ba[i + 1536] = csub(v2, v3);
    }
    {
      float2 v0 = cadd(r0, r2), v2 = csub(r0, r2);
      float2 v1 = cadd(r1, r3), v3 = cmni(csub(r1, r3));
      bb[i]        = cadd(v0, v1);
      bb[i + 512]  = cadd(v2, v3);
      bb[i + 1024] = csub(v0, v1);
      bb[i + 1536] = csub(v2, v3);
    }
  }
  __syncthreads();
}

// Kernel spectrum, 2 channels/block: af[c][k] = rfft_4096(kern[c] zero-padded)
__launch_bounds__(256, 4)
__global__ void fft_kernel_spec(const float* __restrict__ kern, float2* __restrict__ af,
                                const float2* __restrict__ twg, const float2* __restrict__ twh)
{
  __shared__ float2 bx0[2048], bx1[2048];
  const int tid = threadIdx.x;
  const int c0 = xcd_swz((int)blockIdx.x, (int)gridDim.x) * 2;
  const float* ka = kern + (long)c0 * 2048;
  const float* kb = ka + 2048;
  for (int j = tid; j < 1024; j += 256) {
    bx0[j] = *(const float2*)(ka + 2 * j);
    bx1[j] = *(const float2*)(kb + 2 * j);
  }
  __syncthreads();
  fft2048_ip2<true>(bx0, bx1, twg, tid);
  float2* af0 = af + (long)c0 * 2052;
  float2* af1 = af0 + 2052;
  for (int k = tid; k <= 1024; k += 256) {
    const float2 W = twh[k];
    const int kn = (2048 - k) & 2047;
    {
      float2 Zk = bx0[k], Zn = bx0[kn];
      float2 E = make_float2(0.5f * (Zk.x + Zn.x), 0.5f * (Zk.y - Zn.y));
      float2 O = make_float2(0.5f * (Zk.y + Zn.y), 0.5f * (Zn.x - Zk.x));
      float2 WO = cmulf(W, O);
      af0[k] = make_float2(E.x + WO.x, E.y + WO.y);
      if (k != 0 && k != 1024) af0[2048 - k] = make_float2(E.x - WO.x, -(E.y - WO.y));
      if (k == 0)              af0[2048]     = make_float2(E.x - WO.x, -(E.y - WO.y));
    }
    {
      float2 Zk = bx1[k], Zn = bx1[kn];
      float2 E = make_float2(0.5f * (Zk.x + Zn.x), 0.5f * (Zk.y - Zn.y));
      float2 O = make_float2(0.5f * (Zk.y + Zn.y), 0.5f * (Zn.x - Zk.x));
      float2 WO = cmulf(W, O);
      af1[k] = make_float2(E.x + WO.x, E.y + WO.y);
      if (k != 0 && k != 1024) af1[2048 - k] = make_float2(E.x - WO.x, -(E.y - WO.y));
      if (k == 0)              af1[2048]     = make_float2(E.x - WO.x, -(E.y - WO.y));
    }
  }
}

// Conv (IN PLACE on vt), 2 sequences/block (always same channel: 8 seq/chan,
// even-aligned pairs): y = irfft4096(rfft4096(v)*af)[0:2048]
// Spectral unpack/mult/repack is per-thread in-place on pairs {k, 2048-k}.
// XCD swizzle: the 4 blocks sharing a channel's af row land on one XCD.
__launch_bounds__(256, 4)
__global__ void fft_conv(ushort_t* __restrict__ vt, const float2* __restrict__ af,
                         const float2* __restrict__ twg, const float2* __restrict__ twh)
{
  __shared__ float2 bx0[2048], bx1[2048];
  const int tid = threadIdx.x;
  const long s0 = (long)xcd_swz((int)blockIdx.x, (int)gridDim.x) * 2;
  const int c = (int)(s0 >> 3);
  ushort_t* vsa = vt + s0 * 2048;
  ushort_t* vsb = vsa + 2048;
#pragma unroll
  for (int jj = 0; jj < 4; ++jj) {
    const int j = tid + jj * 256;
    unsigned pa = *(const unsigned*)(vsa + 2 * j);
    unsigned pb = *(const unsigned*)(vsb + 2 * j);
    bx0[j] = make_float2(bf2f((ushort_t)(pa & 0xffffu)), bf2f((ushort_t)(pa >> 16)));
    bx1[j] = make_float2(bf2f((ushort_t)(pb & 0xffffu)), bf2f((ushort_t)(pb >> 16)));
  }
  __syncthreads();
  fft2048_ip2<true>(bx0, bx1, twg, tid);   // bx* = Z (packed fwd FFT)
  const float2* afc = af + (long)c * 2052;
  for (int k = tid; k <= 1024; k += 256) {
    const float2 A0 = afc[k], A1 = afc[2048 - k], W = twh[k];
    const float2 cW = make_float2(W.x, -W.y);
    const int kn = (2048 - k) & 2047;
    {
      float2 Zk = bx0[k], Zn = bx0[kn];
      float2 E = make_float2(0.5f * (Zk.x + Zn.x), 0.5f * (Zk.y - Zn.y));
      float2 O = make_float2(0.5f * (Zk.y + Zn.y), 0.5f * (Zn.x - Zk.x));
      float2 WO = cmulf(W, O);
      float2 Xk = make_float2(E.x + WO.x, E.y + WO.y);
      float2 Xn = make_float2(E.x - WO.x, -(E.y - WO.y));
      float2 Pk = cmulf(Xk, A0);
      float2 Pn = cmulf(Xn, A1);
      float2 E2 = make_float2(0.5f * (Pk.x + Pn.x), 0.5f * (Pk.y - Pn.y));
      float2 G  = make_float2(0.5f * (Pk.x - Pn.x), 0.5f * (Pk.y + Pn.y));
      float2 Fo = cmulf(cW, G);
      bx0[k] = make_float2(E2.x - Fo.y, -(E2.y + Fo.x));
      if (k != 0 && k != 1024)
        bx0[2048 - k] = make_float2(E2.x + Fo.y, E2.y - Fo.x);
    }
    {
      float2 Zk = bx1[k], Zn = bx1[kn];
      float2 E = make_float2(0.5f * (Zk.x + Zn.x), 0.5f * (Zk.y - Zn.y));
      float2 O = make_float2(0.5f * (Zk.y + Zn.y), 0.5f * (Zn.x - Zk.x));
      float2 WO = cmulf(W, O);
      float2 Xk = make_float2(E.x + WO.x, E.y + WO.y);
      float2 Xn = make_float2(E.x - WO.x, -(E.y - WO.y));
      float2 Pk = cmulf(Xk, A0);
      float2 Pn = cmulf(Xn, A1);
      float2 E2 = make_float2(0.5f * (Pk.x + Pn.x), 0.5f * (Pk.y - Pn.y));
      float2 G  = make_float2(0.5f * (Pk.x - Pn.x), 0.5f * (Pk.y + Pn.y));
      float2 Fo = cmulf(cW, G);
      bx1[k] = make_float2(E2.x - Fo.y, -(E2.y + Fo.x));
      if (k != 0 && k != 1024)
        bx1[2048 - k] = make_float2(E2.x + Fo.y, E2.y - Fo.x);
    }
  }
  __syncthreads();
  fft2048_ip2<false>(bx0, bx1, twg, tid);  // bx* = FFT(conj(W2))
  const float inv = 1.f / 2048.f;
#pragma unroll
  for (int jj = 0; jj < 4; ++jj) {                    // z[j]=conj(bx[j])/2048
    const int j = tid + jj * 256;
    float2 ra = bx0[j], rb = bx1[j];
    unsigned oa = (unsigned)f2bf(ra.x * inv) | ((unsigned)f2bf(-ra.y * inv) << 16);
    unsigned ob = (unsigned)f2bf(rb.x * inv) | ((unsigned)f2bf(-rb.y * inv) << 16);
    *(unsigned*)(vsa + 2 * j) = oa;
    *(unsigned*)(vsb + 2 * j) = ob;
  }
}

// gate IN PLACE: u[bn][c] *= conv[c][bn]   (conv lives in vt)
__launch_bounds__(256)
__global__ void gate_trans(const ushort_t* __restrict__ convt, ushort_t* __restrict__ u)
{
  __shared__ ushort_t tile[64][65];
  const int bc = (int)blockIdx.x % 24, br = (int)blockIdx.x / 24;
  const int c0 = bc << 6, r0 = br << 6;
  const int tx = threadIdx.x & 63, ty = threadIdx.x >> 6;
  for (int yy = ty; yy < 64; yy += 4)
    tile[yy][tx] = convt[(long)(c0 + yy) * 16384 + r0 + tx];
  __syncthreads();
  for (int yy = ty; yy < 64; yy += 4) {
    long ui = (long)(r0 + yy) * 1536 + c0 + tx;
    float uu = bf2f(u[ui]);
    float cc = bf2f(tile[tx][yy]);
    u[ui] = f2bf(uu * cc);
  }
}

// ===========================================================================
extern "C" void kernel_launch(void* const* d_in, const int* in_sizes, int n_in,
                              void* d_out, int out_size, void* d_ws, size_t ws_size,
                              hipStream_t stream)
{
  const float* x     = (const float*)d_in[0];
  const float* Wu    = (const float*)d_in[1];
  const float* bu    = (const float*)d_in[2];
  const float* Wv    = (const float*)d_in[3];
  const float* bv    = (const float*)d_in[4];
  const float* Wo    = (const float*)d_in[5];
  const float* bo    = (const float*)d_in[6];
  const float* rWin  = (const float*)d_in[7];
  const float* rbin  = (const float*)d_in[8];
  const float* rW    = (const float*)d_in[9];
  const float* rb    = (const float*)d_in[10];
  const float* rWout = (const float*)d_in[11];
  const float* rbout = (const float*)d_in[12];

  char* base = (char*)d_ws;
  size_t off = 0;
  auto alloc = [&](size_t bytes) -> char* {
    size_t r = (off + 255) & ~(size_t)255; off = r + bytes; return base + r;
  };
  ushort_t* wuvt   = (ushort_t*)alloc(3072L * 512 * 2);     // [Wu^T; Wv^T]  3MB
  ushort_t* wot    = (ushort_t*)alloc(512L * 1536 * 2);     // Wo^T        1.5MB
  ushort_t* wrt    = (ushort_t*)alloc(3L * 512 * 512 * 2);  // rpe_W^T x3  1.5MB
  ushort_t* wroutt = (ushort_t*)alloc(1536L * 512 * 2);     // rpe_Wout^T  1.5MB
  float*    buvb   = (float*)   alloc(3072L * 4);           // [bu;bv]
  ushort_t* a0     = (ushort_t*)alloc(2048L * 512 * 2);     // RPE act bf16  2MB
  float2*   af     = (float2*)  alloc(1536L * 2052 * 8);    // spectra    25.2MB
  float2*   twg    = (float2*)  alloc(2048L * 8);           // cis(-2pi j/2048)
  float2*   twh    = (float2*)  alloc(2048L * 8);           // cis(-pi k/2048)
  char*     X      = alloc(16384L * 512 * 2);               // xb | (h+kern) 16MB
  ushort_t* u      = (ushort_t*)alloc(16384L * 1536 * 2);   // u (later gated) 48MB
  ushort_t* vt     = (ushort_t*)alloc(1536L * 16384 * 2);   // v^T / conv^T  48MB
  ushort_t* xb   = (ushort_t*)X;
  float*    h    = (float*)X;
  float*    kern = (float*)(X + 4L * 1024 * 1024);

  const float lng = -0.01005033585350145f;   // ln(0.99)

  // ---- merged prep: weights, biases, x->bf16, twiddles, rpe_h0 ----
  prep_all<<<dim3(14094), dim3(256), 0, stream>>>(
      Wu, Wv, Wo, rW, rWout, bu, bv, x, rWin, rbin,
      wuvt, wot, wrt, wroutt, buvb, xb, twg, twh, a0);

  // ---- u/v projection (fused, v stored transposed) ----
  gemm_bt<3><<<dim3(3072), dim3(256), 0, stream>>>(xb, wuvt, buvb, u, vt,
                                                   16384, 3072, 512, 0.f);

  // ---- RPE chain -> kern[c][n] -> spectra af ----
  for (int i = 0; i < 3; ++i) {
    gemm64_bt<0><<<dim3(256), dim3(256), 0, stream>>>(a0, wrt + (long)i * 512 * 512,
                                                      rb + (long)i * 512, h,
                                                      2048, 512, 512, 0.f);
    rpe_norm<<<dim3(2048), dim3(256), 0, stream>>>(h, a0);
  }
  gemm64_bt<2><<<dim3(768), dim3(256), 0, stream>>>(a0, wroutt, rbout, kern,
                                                    2048, 1536, 512, lng);
  fft_kernel_spec<<<dim3(768), dim3(256), 0, stream>>>(kern, af, twg, twh);

  // ---- FFT conv in place on vt, gate in place into u, out projection ----
  fft_conv<<<dim3(6144), dim3(256), 0, stream>>>(vt, af, twg, twh);
  gate_trans<<<dim3(6144), dim3(256), 0, stream>>>(vt, u);
  gemm_bt<0><<<dim3(512), dim3(256), 0, stream>>>(u, wot, bo, d_out, nullptr,
                                                  16384, 512, 1536, 0.f);
}

// Round 3
// 448.346 us; speedup vs baseline: 1.0223x; 1.0223x over previous
//
#include <hip/hip_runtime.h>
#include <cstdint>

// ============================================================================
// Gtu: u=silu(x@Wu+bu); v=silu(x@Wv+bv); per-channel causal conv of v with
// RPE-generated decayed kernel (rfft4096 via packed cfft2048); out=(u*conv)@Wo+bo
// R10: FFT kernels process their two sequences INTERLEAVED in one float4 LDS
// buffer ({a.re,a.im,b.re,b.im} per index) -> every ds op is one b128 serving
// both sequences at one address: LDS instruction count and address math halve.
// XCD swizzle REVERTED on FFT kernels (R9: -10us regression there; kept on
// GEMMs where it gained ~9us). R8: in-place register-staged Stockham, 32KiB.
// ============================================================================

typedef unsigned short ushort_t;                                    // bf16 bits
typedef __attribute__((ext_vector_type(8))) short short8;           // MFMA A/B frag
typedef __attribute__((ext_vector_type(4))) float f32x4;            // MFMA acc

#define AS1 __attribute__((address_space(1)))
#define AS3 __attribute__((address_space(3)))

// per-buffer swizzles (bijections on [0,2048) indices) [R4 HW-verified]
#define SW1(j) ((j) ^ (((j) >> 4) & 15))        // stage1-output positions
#define SW2(j) ((j) ^ ((((j) >> 6) & 7) << 1))  // stage2-output positions

// XCD-aware chunked swizzle (GEMMs only): bijective when nwg % 8 == 0.
__device__ __forceinline__ int xcd_swz(int bid, int nwg) {
  return (bid & 7) * (nwg >> 3) + (bid >> 3);
}

__device__ __forceinline__ float bf2f(ushort_t b) {
  union { unsigned u; float f; } x; x.u = ((unsigned)b) << 16; return x.f;
}
__device__ __forceinline__ ushort_t f2bf(float f) {
  union { float f; unsigned u; } x; x.f = f;
  unsigned r = x.u + 0x7fffu + ((x.u >> 16) & 1u);   // RNE
  return (ushort_t)(r >> 16);
}

// CK-style addrspace cast (flat LDS addr low 32 bits == LDS offset on gfx9)
__device__ __forceinline__ void gload_lds16(const void* g, void* l) {
  auto gp = reinterpret_cast<const AS1 unsigned*>(reinterpret_cast<uintptr_t>(g));
  auto lp = reinterpret_cast<AS3 unsigned*>(reinterpret_cast<uintptr_t>(l));
  __builtin_amdgcn_global_load_lds(gp, lp, 16, 0, 0);
}

// ---------------------------------------------------------------------------
// bf16 GEMM: C = A[M][K] @ Bt[N][K]^T (+bias). 128x128x64 tiles, 4 waves.
// MODE 0: fp32 store. MODE 3: silu; col<1536 -> u; col>=1536 -> vt transposed.
// ---------------------------------------------------------------------------
template<int MODE>
__launch_bounds__(256, 2)
__global__ void gemm_bt(const ushort_t* __restrict__ A, const ushort_t* __restrict__ Bt,
                        const float* __restrict__ bias, void* __restrict__ Cout,
                        void* __restrict__ Cout2, int M, int N, int K, float lng)
{
  __shared__ ushort_t As[128 * 64];
  __shared__ ushort_t Bs[128 * 64];
  const int tid  = threadIdx.x;
  const int wave = tid >> 6, lane = tid & 63;
  const int nb = N >> 7;
  const int lbid = xcd_swz((int)blockIdx.x, (int)gridDim.x);
  const int bm = lbid / nb, bn = lbid % nb;
  const int m0 = bm << 7, n0 = bn << 7;
  const int lrow = lane & 15, quad = lane >> 4;
  const int wm = (wave >> 1) << 6, wn = (wave & 1) << 6;
  const int srow = lane >> 3;
  const int scol = (lane & 7) << 3;

  f32x4 acc[4][4] = {};

  for (int kt = 0; kt < K; kt += 64) {
    __syncthreads();
#pragma unroll
    for (int i = 0; i < 4; ++i) {
      const int ci  = i * 4 + wave;
      const int row = ci * 8 + srow;
      gload_lds16(A  + (long)(m0 + row) * K + kt + scol, (void*)&As[ci * 512]);
      gload_lds16(Bt + (long)(n0 + row) * K + kt + scol, (void*)&Bs[ci * 512]);
    }
    __syncthreads();
#pragma unroll
    for (int s = 0; s < 2; ++s) {
      short8 afr[4], bfr[4];
#pragma unroll
      for (int i = 0; i < 4; ++i)
        afr[i] = *(const short8*)&As[(wm + i * 16 + lrow) * 64 + s * 32 + quad * 8];
#pragma unroll
      for (int j = 0; j < 4; ++j)
        bfr[j] = *(const short8*)&Bs[(wn + j * 16 + lrow) * 64 + s * 32 + quad * 8];
#pragma unroll
      for (int i = 0; i < 4; ++i)
#pragma unroll
        for (int j = 0; j < 4; ++j)
          acc[i][j] = __builtin_amdgcn_mfma_f32_16x16x32_bf16(afr[i], bfr[j], acc[i][j], 0, 0, 0);
    }
  }

#pragma unroll
  for (int i = 0; i < 4; ++i) {
    const int rowb = m0 + wm + i * 16 + quad * 4;
#pragma unroll
    for (int j = 0; j < 4; ++j) {
      const int col = n0 + wn + j * 16 + lrow;
      const float bv = bias[col];
      if (MODE == 0) {
#pragma unroll
        for (int r = 0; r < 4; ++r)
          ((float*)Cout)[(long)(rowb + r) * N + col] = acc[i][j][r] + bv;
      } else {  // MODE 3
        if (col < 1536) {
#pragma unroll
          for (int r = 0; r < 4; ++r) {
            float val = acc[i][j][r] + bv;
            float sv = val / (1.f + __expf(-val));
            ((ushort_t*)Cout)[(long)(rowb + r) * 1536 + col] = f2bf(sv);
          }
        } else {
          union { ushort_t h[4]; uint2 u2; } pk;
#pragma unroll
          for (int r = 0; r < 4; ++r) {
            float val = acc[i][j][r] + bv;
            float sv = val / (1.f + __expf(-val));
            pk.h[r] = f2bf(sv);
          }
          *(uint2*)((ushort_t*)Cout2 + (long)(col - 1536) * 16384 + rowb) = pk.u2;
        }
      }
    }
  }
}

// ---------------------------------------------------------------------------
// Small-GEMM variant: 64x64 tiles, 4 waves (each 32x32). Same staging scheme.
// MODE 0: fp32 store. MODE 2: *gamma^row, transposed fp32 store (RPE kernel).
// ---------------------------------------------------------------------------
template<int MODE>
__launch_bounds__(256, 2)
__global__ void gemm64_bt(const ushort_t* __restrict__ A, const ushort_t* __restrict__ Bt,
                          const float* __restrict__ bias, float* __restrict__ Cout,
                          int M, int N, int K, float lng)
{
  __shared__ ushort_t As[64 * 64];
  __shared__ ushort_t Bs[64 * 64];
  const int tid = threadIdx.x, wave = tid >> 6, lane = tid & 63;
  const int nb = N >> 6;
  const int lbid = xcd_swz((int)blockIdx.x, (int)gridDim.x);
  const int bm = lbid / nb, bn = lbid % nb;
  const int m0 = bm << 6, n0 = bn << 6;
  const int lrow = lane & 15, quad = lane >> 4;
  const int wm = (wave >> 1) << 5, wn = (wave & 1) << 5;
  const int srow = lane >> 3, scol = (lane & 7) << 3;

  f32x4 acc[2][2] = {};

  for (int kt = 0; kt < K; kt += 64) {
    __syncthreads();
#pragma unroll
    for (int i = 0; i < 2; ++i) {
      const int ci = i * 4 + wave;          // 8 chunks of 8 rows
      const int row = ci * 8 + srow;
      gload_lds16(A  + (long)(m0 + row) * K + kt + scol, (void*)&As[ci * 512]);
      gload_lds16(Bt + (long)(n0 + row) * K + kt + scol, (void*)&Bs[ci * 512]);
    }
    __syncthreads();
#pragma unroll
    for (int s = 0; s < 2; ++s) {
      short8 afr[2], bfr[2];
#pragma unroll
      for (int i = 0; i < 2; ++i)
        afr[i] = *(const short8*)&As[(wm + i * 16 + lrow) * 64 + s * 32 + quad * 8];
#pragma unroll
      for (int j = 0; j < 2; ++j)
        bfr[j] = *(const short8*)&Bs[(wn + j * 16 + lrow) * 64 + s * 32 + quad * 8];
#pragma unroll
      for (int i = 0; i < 2; ++i)
#pragma unroll
        for (int j = 0; j < 2; ++j)
          acc[i][j] = __builtin_amdgcn_mfma_f32_16x16x32_bf16(afr[i], bfr[j], acc[i][j], 0, 0, 0);
    }
  }

#pragma unroll
  for (int i = 0; i < 2; ++i) {
    const int rowb = m0 + wm + i * 16 + quad * 4;
#pragma unroll
    for (int j = 0; j < 2; ++j) {
      const int col = n0 + wn + j * 16 + lrow;
      const float bv = bias[col];
#pragma unroll
      for (int r = 0; r < 4; ++r) {
        const int row = rowb + r;
        float val = acc[i][j][r] + bv;
        if (MODE == 0) Cout[(long)row * N + col] = val;
        else           Cout[(long)col * M + row] = val * __expf(lng * (float)row);
      }
    }
  }
}

// ---------------------------------------------------------------------------
// RPE row op: srms -> relu -> bf16
// ---------------------------------------------------------------------------
__device__ __forceinline__ void srms_relu_store(float v0, float v1, ushort_t* out,
                                                long rowbase, int tid)
{
  float ss = v0 * v0 + v1 * v1;
#pragma unroll
  for (int off = 32; off; off >>= 1) ss += __shfl_down(ss, off);
  __shared__ float ps[4];
  const int wave = tid >> 6, lane = tid & 63;
  if (lane == 0) ps[wave] = ss;
  __syncthreads();
  float tot = ps[0] + ps[1] + ps[2] + ps[3];
  float sc = 1.f / (sqrtf(tot * (1.f / 512.f)) + 1e-6f);
  out[rowbase + tid]       = f2bf(fmaxf(v0 * sc, 0.f));
  out[rowbase + tid + 256] = f2bf(fmaxf(v1 * sc, 0.f));
}

__launch_bounds__(256)
__global__ void rpe_norm(const float* __restrict__ h, ushort_t* __restrict__ out)
{
  const int n = blockIdx.x, tid = threadIdx.x;
  float v0 = h[(long)n * 512 + tid];
  float v1 = h[(long)n * 512 + tid + 256];
  srms_relu_store(v0, v1, out, (long)n * 512, tid);
}

// ---------------------------------------------------------------------------
// Merged prep: 6x weight transpose | bias concat | x->bf16 | twiddles | rpe_h0
// ---------------------------------------------------------------------------
__device__ __forceinline__ void wtrans_body(const float* __restrict__ src,
                                            ushort_t* __restrict__ dst,
                                            int K, int N, int lb, int tid,
                                            float (*tile)[33])
{
  const int nbx = N >> 5;
  const int bx = lb % nbx, by = lb / nbx;
  const int n0 = bx << 5, k0 = by << 5;
  const int tx = tid & 31, ty = tid >> 5;
  for (int yy = ty; yy < 32; yy += 8)
    tile[yy][tx] = src[(long)(k0 + yy) * N + n0 + tx];
  __syncthreads();
  for (int yy = ty; yy < 32; yy += 8)
    dst[(long)(n0 + yy) * K + k0 + tx] = f2bf(tile[tx][yy]);
}

__launch_bounds__(256)
__global__ void prep_all(const float* __restrict__ Wu, const float* __restrict__ Wv,
                         const float* __restrict__ Wo, const float* __restrict__ rW,
                         const float* __restrict__ rWout,
                         const float* __restrict__ bu, const float* __restrict__ bv,
                         const float* __restrict__ x,
                         const float* __restrict__ rWin, const float* __restrict__ rbin,
                         ushort_t* __restrict__ wuvt, ushort_t* __restrict__ wot,
                         ushort_t* __restrict__ wrt, ushort_t* __restrict__ wroutt,
                         float* __restrict__ buvb, ushort_t* __restrict__ xb,
                         float2* __restrict__ twg, float2* __restrict__ twh,
                         ushort_t* __restrict__ a0)
{
  __shared__ float tile[32][33];
  const int bid = blockIdx.x, tid = threadIdx.x;
  if (bid < 3840) {
    const float* src; ushort_t* dst; int K, N, lb;
    if (bid < 768)       { src = Wu;    dst = wuvt;              K = 512;  N = 1536; lb = bid; }
    else if (bid < 1536) { src = Wv;    dst = wuvt + 1536L*512;  K = 512;  N = 1536; lb = bid - 768; }
    else if (bid < 2304) { src = Wo;    dst = wot;               K = 1536; N = 512;  lb = bid - 1536; }
    else if (bid < 2560) { src = rW;              dst = wrt;              K = 512; N = 512; lb = bid - 2304; }
    else if (bid < 2816) { src = rW + 512L*512;   dst = wrt + 512L*512;   K = 512; N = 512; lb = bid - 2560; }
    else if (bid < 3072) { src = rW + 2L*512*512; dst = wrt + 2L*512*512; K = 512; N = 512; lb = bid - 2816; }
    else                 { src = rWout; dst = wroutt;            K = 512;  N = 1536; lb = bid - 3072; }
    wtrans_body(src, dst, K, N, lb, tid, tile);
  } else if (bid < 3846) {
    int i = (bid - 3840) * 256 + tid;
    if (i < 1536) { buvb[i] = bu[i]; buvb[1536 + i] = bv[i]; }
  } else if (bid < 12038) {
    long i = (long)(bid - 3846) * 1024 + tid * 4;
    float4 f = *(const float4*)(x + i);
    unsigned lo = (unsigned)f2bf(f.x) | ((unsigned)f2bf(f.y) << 16);
    unsigned hi = (unsigned)f2bf(f.z) | ((unsigned)f2bf(f.w) << 16);
    *(uint2*)(xb + i) = make_uint2(lo, hi);
  } else if (bid < 12046) {
    int j = (bid - 12038) * 256 + tid;    // 0..2047
    float s, c;
    __sincosf((float)j * (6.283185307179586f / 2048.f), &s, &c);
    twg[j] = make_float2(c, -s);
    float s2, c2;
    __sincosf((float)j * (3.14159265358979f / 2048.f), &s2, &c2);
    twh[j] = make_float2(c2, -s2);
  } else {
    const int n = bid - 12046;            // 0..2047
    const float fn = (float)n;
    float v0 = fn * rWin[tid] + rbin[tid];
    float v1 = fn * rWin[tid + 256] + rbin[tid + 256];
    srms_relu_store(v0, v1, a0, (long)n * 512, tid);
  }
}

// ---------------------------------------------------------------------------
// Block-level Stockham FFT-2048 (radix 8,8,8,4), TWO sequences interleaved
// in ONE float4 buffer: elem j = {a_re, a_im, b_re, b_im}. IN PLACE (R8):
// read 8 elems/thread -> compute -> barrier -> write back, same buffer,
// R4's HW-verified Stockham output indices (SW1/SW2 swizzles preserved).
// ---------------------------------------------------------------------------
__device__ __forceinline__ float2 cmulf(float2 a, float2 b) {
  return make_float2(a.x * b.x - a.y * b.y, a.x * b.y + a.y * b.x);
}
// dual-complex (float4 = two complex) helpers
__device__ __forceinline__ float4 c2add(float4 p, float4 q){
  return make_float4(p.x+q.x, p.y+q.y, p.z+q.z, p.w+q.w);
}
__device__ __forceinline__ float4 c2sub(float4 p, float4 q){
  return make_float4(p.x-q.x, p.y-q.y, p.z-q.z, p.w-q.w);
}
__device__ __forceinline__ float4 c2mni(float4 z){        // z * (-i), both halves
  return make_float4(z.y, -z.x, z.w, -z.z);
}
__device__ __forceinline__ float4 c2w8(float4 z){         // z * cis(-pi/4)
  const float s = 0.70710678118654752f;
  return make_float4(s*(z.x+z.y), s*(z.y-z.x), s*(z.z+z.w), s*(z.w-z.z));
}
__device__ __forceinline__ float4 c2w83(float4 z){        // z * cis(-3pi/4)
  const float s = 0.70710678118654752f;
  return make_float4(s*(z.y-z.x), -s*(z.x+z.y), s*(z.w-z.z), -s*(z.z+z.w));
}
__device__ __forceinline__ float4 c2mul(float4 z, float2 w){  // both halves * w
  return make_float4(z.x*w.x - z.y*w.y, z.x*w.y + z.y*w.x,
                     z.z*w.x - z.w*w.y, z.z*w.y + z.w*w.x);
}

// dual DFT-8 combine (twiddles pre-applied) [structure R4 HW-verified]
__device__ __forceinline__ void dft8d(const float4* u, float4* y)
{
  float4 a0=c2add(u[0],u[4]), a1=c2add(u[1],u[5]), a2=c2add(u[2],u[6]), a3=c2add(u[3],u[7]);
  float4 b0=c2sub(u[0],u[4]), b1=c2w8(c2sub(u[1],u[5])), b2=c2mni(c2sub(u[2],u[6])), b3=c2w83(c2sub(u[3],u[7]));
  float4 c0=c2add(a0,a2), c1=c2sub(a0,a2), c2=c2add(a1,a3), c3=c2mni(c2sub(a1,a3));
  y[0]=c2add(c0,c2); y[2]=c2add(c1,c3); y[4]=c2sub(c0,c2); y[6]=c2sub(c1,c3);
  float4 d0=c2add(b0,b2), d1=c2sub(b0,b2), d2=c2add(b1,b3), d3=c2mni(c2sub(b1,b3));
  y[1]=c2add(d0,d2); y[3]=c2add(d1,d3); y[5]=c2sub(d0,d2); y[7]=c2sub(d1,d3);
}
__device__ __forceinline__ void dft8d_hz(const float4* u, float4* y)   // u[4..7]=0
{
  float4 b1=c2w8(u[1]), b2=c2mni(u[2]), b3=c2w83(u[3]);
  float4 c0=c2add(u[0],u[2]), c1=c2sub(u[0],u[2]), c2=c2add(u[1],u[3]), c3=c2mni(c2sub(u[1],u[3]));
  y[0]=c2add(c0,c2); y[2]=c2add(c1,c3); y[4]=c2sub(c0,c2); y[6]=c2sub(c1,c3);
  float4 d0=c2add(u[0],b2), d1=c2sub(u[0],b2), d2=c2add(b1,b3), d3=c2mni(c2sub(b1,b3));
  y[1]=c2add(d0,d2); y[3]=c2add(d1,d3); y[5]=c2sub(d0,d2); y[7]=c2sub(d1,d3);
}

template<bool HZ>
__device__ void fft2048_ip4(float4* b, const float2* __restrict__ tw, int tid)
{
  float4 u[8], y[8];
  // ---- stage 1: radix-8, p=1 (no twiddles) ----
  {
    const int i = tid;
#pragma unroll
    for (int m = 0; m < (HZ ? 4 : 8); ++m) u[m] = b[i + 256*m];
    if (HZ) dft8d_hz(u, y); else dft8d(u, y);
    __syncthreads();                         // all reads done before any write
    const int j = i << 3;
#pragma unroll
    for (int m = 0; m < 8; ++m) b[SW1(j + m)] = y[m];
  }
  __syncthreads();
  // ---- stage 2: radix-8, p=8 (tw step 32) ----
  {
    const int i = tid, k = i & 7, tb = k << 5;
    float2 w[8];
#pragma unroll
    for (int m = 1; m < 8; ++m) w[m] = tw[m * tb];
#pragma unroll
    for (int m = 0; m < 8; ++m) u[m] = b[SW1(i + 256*m)];
#pragma unroll
    for (int m = 1; m < 8; ++m) u[m] = c2mul(u[m], w[m]);
    dft8d(u, y);
    __syncthreads();
    const int j = ((i - k) << 3) + k;
#pragma unroll
    for (int m = 0; m < 8; ++m) b[SW2(j + 8*m)] = y[m];
  }
  __syncthreads();
  // ---- stage 3: radix-8, p=64 (tw step 4) ----
  {
    const int i = tid, k = i & 63, tb = k << 2;
    float2 w[8];
#pragma unroll
    for (int m = 1; m < 8; ++m) w[m] = tw[m * tb];
#pragma unroll
    for (int m = 0; m < 8; ++m) u[m] = b[SW2(i + 256*m)];
#pragma unroll
    for (int m = 1; m < 8; ++m) u[m] = c2mul(u[m], w[m]);
    dft8d(u, y);
    __syncthreads();
    const int j = ((i - k) << 3) + k;
#pragma unroll
    for (int m = 0; m < 8; ++m) b[j + 64*m] = y[m];
  }
  __syncthreads();
  // ---- stage 4: radix-4, p=512 (k=i, j=i): per-thread in-place ----
#pragma unroll
  for (int hh = 0; hh < 2; ++hh) {
    const int i = tid + (hh << 8);
    float2 w1 = tw[i], w2 = tw[2 * i], w3 = tw[3 * i];
    float4 q0 = b[i], q1 = b[i + 512], q2 = b[i + 1024], q3 = b[i + 1536];
    q1 = c2mul(q1, w1); q2 = c2mul(q2, w2); q3 = c2mul(q3, w3);
    float4 v0 = c2add(q0, q2), v2 = c2sub(q0, q2);
    float4 v1 = c2add(q1, q3), v3 = c2mni(c2sub(q1, q3));
    b[i]        = c2add(v0, v1);
    b[i + 512]  = c2add(v2, v3);
    b[i + 1024] = c2sub(v0, v1);
    b[i + 1536] = c2sub(v2, v3);
  }
  __syncthreads();
}

// Kernel spectrum, 2 channels/block: af[c][k] = rfft_4096(kern[c] zero-padded)
__launch_bounds__(256, 4)
__global__ void fft_kernel_spec(const float* __restrict__ kern, float2* __restrict__ af,
                                const float2* __restrict__ twg, const float2* __restrict__ twh)
{
  __shared__ float4 bx[2048];
  const int tid = threadIdx.x;
  const int c0 = (int)blockIdx.x * 2;
  const float* ka = kern + (long)c0 * 2048;
  const float* kb = ka + 2048;
  for (int j = tid; j < 1024; j += 256) {
    float2 A = *(const float2*)(ka + 2 * j);
    float2 B = *(const float2*)(kb + 2 * j);
    bx[j] = make_float4(A.x, A.y, B.x, B.y);
  }
  __syncthreads();
  fft2048_ip4<true>(bx, twg, tid);
  float2* af0 = af + (long)c0 * 2052;
  float2* af1 = af0 + 2052;
  for (int k = tid; k <= 1024; k += 256) {
    const float2 W = twh[k];
    const int kn = (2048 - k) & 2047;
    const float4 Zk4 = bx[k], Zn4 = bx[kn];
    {
      float2 Zk = make_float2(Zk4.x, Zk4.y), Zn = make_float2(Zn4.x, Zn4.y);
      float2 E = make_float2(0.5f * (Zk.x + Zn.x), 0.5f * (Zk.y - Zn.y));
      float2 O = make_float2(0.5f * (Zk.y + Zn.y), 0.5f * (Zn.x - Zk.x));
      float2 WO = cmulf(W, O);
      af0[k] = make_float2(E.x + WO.x, E.y + WO.y);
      if (k != 0 && k != 1024) af0[2048 - k] = make_float2(E.x - WO.x, -(E.y - WO.y));
      if (k == 0)              af0[2048]     = make_float2(E.x - WO.x, -(E.y - WO.y));
    }
    {
      float2 Zk = make_float2(Zk4.z, Zk4.w), Zn = make_float2(Zn4.z, Zn4.w);
      float2 E = make_float2(0.5f * (Zk.x + Zn.x), 0.5f * (Zk.y - Zn.y));
      float2 O = make_float2(0.5f * (Zk.y + Zn.y), 0.5f * (Zn.x - Zk.x));
      float2 WO = cmulf(W, O);
      af1[k] = make_float2(E.x + WO.x, E.y + WO.y);
      if (k != 0 && k != 1024) af1[2048 - k] = make_float2(E.x - WO.x, -(E.y - WO.y));
      if (k == 0)              af1[2048]     = make_float2(E.x - WO.x, -(E.y - WO.y));
    }
  }
}

// Conv (IN PLACE on vt), 2 sequences/block (always same channel: 8 seq/chan,
// even-aligned pairs): y = irfft4096(rfft4096(v)*af)[0:2048]
// Spectral unpack/mult/repack is per-thread in-place on pairs {k, 2048-k}.
__launch_bounds__(256, 4)
__global__ void fft_conv(ushort_t* __restrict__ vt, const float2* __restrict__ af,
                         const float2* __restrict__ twg, const float2* __restrict__ twh)
{
  __shared__ float4 bx[2048];
  const int tid = threadIdx.x;
  const long s0 = (long)blockIdx.x * 2;
  const int c = (int)(s0 >> 3);
  ushort_t* vsa = vt + s0 * 2048;
  ushort_t* vsb = vsa + 2048;
#pragma unroll
  for (int jj = 0; jj < 4; ++jj) {
    const int j = tid + jj * 256;
    unsigned pa = *(const unsigned*)(vsa + 2 * j);
    unsigned pb = *(const unsigned*)(vsb + 2 * j);
    bx[j] = make_float4(bf2f((ushort_t)(pa & 0xffffu)), bf2f((ushort_t)(pa >> 16)),
                        bf2f((ushort_t)(pb & 0xffffu)), bf2f((ushort_t)(pb >> 16)));
  }
  __syncthreads();
  fft2048_ip4<true>(bx, twg, tid);   // bx = Z (packed fwd FFT, both seqs)
  const float2* afc = af + (long)c * 2052;
  for (int k = tid; k <= 1024; k += 256) {
    const float2 A0 = afc[k], A1 = afc[2048 - k], W = twh[k];
    const float2 cW = make_float2(W.x, -W.y);
    const int kn = (2048 - k) & 2047;
    const float4 Zk4 = bx[k], Zn4 = bx[kn];
    float2 ya0, yn0, ya1, yn1;
    {
      float2 Zk = make_float2(Zk4.x, Zk4.y), Zn = make_float2(Zn4.x, Zn4.y);
      float2 E = make_float2(0.5f * (Zk.x + Zn.x), 0.5f * (Zk.y - Zn.y));
      float2 O = make_float2(0.5f * (Zk.y + Zn.y), 0.5f * (Zn.x - Zk.x));
      float2 WO = cmulf(W, O);
      float2 Xk = make_float2(E.x + WO.x, E.y + WO.y);
      float2 Xn = make_float2(E.x - WO.x, -(E.y - WO.y));
      float2 Pk = cmulf(Xk, A0);
      float2 Pn = cmulf(Xn, A1);
      float2 E2 = make_float2(0.5f * (Pk.x + Pn.x), 0.5f * (Pk.y - Pn.y));
      float2 G  = make_float2(0.5f * (Pk.x - Pn.x), 0.5f * (Pk.y + Pn.y));
      float2 Fo = cmulf(cW, G);
      ya0 = make_float2(E2.x - Fo.y, -(E2.y + Fo.x));
      yn0 = make_float2(E2.x + Fo.y, E2.y - Fo.x);
    }
    {
      float2 Zk = make_float2(Zk4.z, Zk4.w), Zn = make_float2(Zn4.z, Zn4.w);
      float2 E = make_float2(0.5f * (Zk.x + Zn.x), 0.5f * (Zk.y - Zn.y));
      float2 O = make_float2(0.5f * (Zk.y + Zn.y), 0.5f * (Zn.x - Zk.x));
      float2 WO = cmulf(W, O);
      float2 Xk = make_float2(E.x + WO.x, E.y + WO.y);
      float2 Xn = make_float2(E.x - WO.x, -(E.y - WO.y));
      float2 Pk = cmulf(Xk, A0);
      float2 Pn = cmulf(Xn, A1);
      float2 E2 = make_float2(0.5f * (Pk.x + Pn.x), 0.5f * (Pk.y - Pn.y));
      float2 G  = make_float2(0.5f * (Pk.x - Pn.x), 0.5f * (Pk.y + Pn.y));
      float2 Fo = cmulf(cW, G);
      ya1 = make_float2(E2.x - Fo.y, -(E2.y + Fo.x));
      yn1 = make_float2(E2.x + Fo.y, E2.y - Fo.x);
    }
    bx[k] = make_float4(ya0.x, ya0.y, ya1.x, ya1.y);
    if (k != 0 && k != 1024)
      bx[2048 - k] = make_float4(yn0.x, yn0.y, yn1.x, yn1.y);
  }
  __syncthreads();
  fft2048_ip4<false>(bx, twg, tid);  // bx = FFT(conj(W2)), both seqs
  const float inv = 1.f / 2048.f;
#pragma unroll
  for (int jj = 0; jj < 4; ++jj) {                    // z[j]=conj(bx[j])/2048
    const int j = tid + jj * 256;
    float4 r = bx[j];
    unsigned oa = (unsigned)f2bf(r.x * inv) | ((unsigned)f2bf(-r.y * inv) << 16);
    unsigned ob = (unsigned)f2bf(r.z * inv) | ((unsigned)f2bf(-r.w * inv) << 16);
    *(unsigned*)(vsa + 2 * j) = oa;
    *(unsigned*)(vsb + 2 * j) = ob;
  }
}

// gate IN PLACE: u[bn][c] *= conv[c][bn]   (conv lives in vt)
__launch_bounds__(256)
__global__ void gate_trans(const ushort_t* __restrict__ convt, ushort_t* __restrict__ u)
{
  __shared__ ushort_t tile[64][65];
  const int bc = (int)blockIdx.x % 24, br = (int)blockIdx.x / 24;
  const int c0 = bc << 6, r0 = br << 6;
  const int tx = threadIdx.x & 63, ty = threadIdx.x >> 6;
  for (int yy = ty; yy < 64; yy += 4)
    tile[yy][tx] = convt[(long)(c0 + yy) * 16384 + r0 + tx];
  __syncthreads();
  for (int yy = ty; yy < 64; yy += 4) {
    long ui = (long)(r0 + yy) * 1536 + c0 + tx;
    float uu = bf2f(u[ui]);
    float cc = bf2f(tile[tx][yy]);
    u[ui] = f2bf(uu * cc);
  }
}

// ===========================================================================
extern "C" void kernel_launch(void* const* d_in, const int* in_sizes, int n_in,
                              void* d_out, int out_size, void* d_ws, size_t ws_size,
                              hipStream_t stream)
{
  const float* x     = (const float*)d_in[0];
  const float* Wu    = (const float*)d_in[1];
  const float* bu    = (const float*)d_in[2];
  const float* Wv    = (const float*)d_in[3];
  const float* bv    = (const float*)d_in[4];
  const float* Wo    = (const float*)d_in[5];
  const float* bo    = (const float*)d_in[6];
  const float* rWin  = (const float*)d_in[7];
  const float* rbin  = (const float*)d_in[8];
  const float* rW    = (const float*)d_in[9];
  const float* rb    = (const float*)d_in[10];
  const float* rWout = (const float*)d_in[11];
  const float* rbout = (const float*)d_in[12];

  char* base = (char*)d_ws;
  size_t off = 0;
  auto alloc = [&](size_t bytes) -> char* {
    size_t r = (off + 255) & ~(size_t)255; off = r + bytes; return base + r;
  };
  ushort_t* wuvt   = (ushort_t*)alloc(3072L * 512 * 2);     // [Wu^T; Wv^T]  3MB
  ushort_t* wot    = (ushort_t*)alloc(512L * 1536 * 2);     // Wo^T        1.5MB
  ushort_t* wrt    = (ushort_t*)alloc(3L * 512 * 512 * 2);  // rpe_W^T x3  1.5MB
  ushort_t* wroutt = (ushort_t*)alloc(1536L * 512 * 2);     // rpe_Wout^T  1.5MB
  float*    buvb   = (float*)   alloc(3072L * 4);           // [bu;bv]
  ushort_t* a0     = (ushort_t*)alloc(2048L * 512 * 2);     // RPE act bf16  2MB
  float2*   af     = (float2*)  alloc(1536L * 2052 * 8);    // spectra    25.2MB
  float2*   twg    = (float2*)  alloc(2048L * 8);           // cis(-2pi j/2048)
  float2*   twh    = (float2*)  alloc(2048L * 8);           // cis(-pi k/2048)
  char*     X      = alloc(16384L * 512 * 2);               // xb | (h+kern) 16MB
  ushort_t* u      = (ushort_t*)alloc(16384L * 1536 * 2);   // u (later gated) 48MB
  ushort_t* vt     = (ushort_t*)alloc(1536L * 16384 * 2);   // v^T / conv^T  48MB
  ushort_t* xb   = (ushort_t*)X;
  float*    h    = (float*)X;
  float*    kern = (float*)(X + 4L * 1024 * 1024);

  const float lng = -0.01005033585350145f;   // ln(0.99)

  // ---- merged prep: weights, biases, x->bf16, twiddles, rpe_h0 ----
  prep_all<<<dim3(14094), dim3(256), 0, stream>>>(
      Wu, Wv, Wo, rW, rWout, bu, bv, x, rWin, rbin,
      wuvt, wot, wrt, wroutt, buvb, xb, twg, twh, a0);

  // ---- u/v projection (fused, v stored transposed) ----
  gemm_bt<3><<<dim3(3072), dim3(256), 0, stream>>>(xb, wuvt, buvb, u, vt,
                                                   16384, 3072, 512, 0.f);

  // ---- RPE chain -> kern[c][n] -> spectra af ----
  for (int i = 0; i < 3; ++i) {
    gemm64_bt<0><<<dim3(256), dim3(256), 0, stream>>>(a0, wrt + (long)i * 512 * 512,
                                                      rb + (long)i * 512, h,
                                                      2048, 512, 512, 0.f);
    rpe_norm<<<dim3(2048), dim3(256), 0, stream>>>(h, a0);
  }
  gemm64_bt<2><<<dim3(768), dim3(256), 0, stream>>>(a0, wroutt, rbout, kern,
                                                    2048, 1536, 512, lng);
  fft_kernel_spec<<<dim3(768), dim3(256), 0, stream>>>(kern, af, twg, twh);

  // ---- FFT conv in place on vt, gate in place into u, out projection ----
  fft_conv<<<dim3(6144), dim3(256), 0, stream>>>(vt, af, twg, twh);
  gate_trans<<<dim3(6144), dim3(256), 0, stream>>>(vt, u);
  gemm_bt<0><<<dim3(512), dim3(256), 0, stream>>>(u, wot, bo, d_out, nullptr,
                                                  16384, 512, 1536, 0.f);
}